// Round 4
// baseline (275.205 us; speedup 1.0000x reference)
//
#include <hip/hip_runtime.h>

#define NN 20000
#define NE 640000
#define CH 128
#define HC 64          // half-channel
#define NG 64
#define NSLICE (NN / 8)

typedef unsigned short u16;
typedef __attribute__((ext_vector_type(8))) short short8;   // 8 bf16 (4 VGPRs)
typedef __attribute__((ext_vector_type(4))) float floatx4;  // 4 fp32 acc

__device__ __forceinline__ float b2f(u16 u) {
    union { float f; unsigned int i; } v; v.i = ((unsigned int)u) << 16; return v.f;
}
__device__ __forceinline__ u16 f2b(float f) {
    unsigned int u = __float_as_uint(f);
    u += 0x7fff + ((u >> 16) & 1);          // RNE
    return (u16)(u >> 16);
}

// ---- convert x -> bf16 channel-split halves; weights -> bf16 B-frag order --
// split: xh[h][n][c2] , h = c>>6, c2 = c&63  (each half 2.56MB: fits 4MiB L2)
__global__ __launch_bounds__(256) void cvt_all(const float* __restrict__ x, u16* __restrict__ xb,
                                               const float* __restrict__ W1a, const float* __restrict__ W1b,
                                               const float* __restrict__ W2a, const float* __restrict__ W2b,
                                               u16* __restrict__ wt) {
    int b = blockIdx.x;
    if (b < 2500) {                                   // x: 2.56M elems, 4/thread
        int idx = (b * 256 + threadIdx.x) * 4;
        int n = idx >> 7, c = idx & 127;
        int half = c >> 6, c2 = c & 63;
        float4 v = *(const float4*)(x + idx);
        ushort4 o = make_ushort4(f2b(v.x), f2b(v.y), f2b(v.z), f2b(v.w));
        *(ushort4*)(xb + (size_t)half * NN * HC + (size_t)n * HC + c2) = o;
    } else {                                          // weights: 4 x 16384 elems
        int wi = b - 2500;                            // 0..255
        int m = wi >> 6;
        int r = (wi & 63) * 256 + threadIdx.x;        // 0..16383
        int j = r & 7, l16 = (r >> 3) & 15, quad = (r >> 7) & 3;
        int kc = (r >> 9) & 3, ct = (r >> 11) & 7;
        int n = ct * 16 + l16, k = kc * 32 + quad * 8 + j;
        const float* W = (m == 0) ? W1a : (m == 1) ? W1b : (m == 2) ? W2a : W2b;
        wt[m * 16384 + r] = f2b(W[k * 128 + n]);
    }
}

// ---- CSR pass A: histogram + rank, packed (dst | rank<<15) ----------------
__global__ __launch_bounds__(256) void pass_rank(const int* __restrict__ ei,
                                                 int* __restrict__ cnt, int* __restrict__ pk) {
    int e = blockIdx.x * 256 + threadIdx.x;
    if (e < NE) {
        int dst = ei[NE + e];
        int r = atomicAdd(&cnt[dst], 1);
        pk[e] = dst | (r << 15);
    }
}

// ---- scan cnt -> off ------------------------------------------------------
__global__ void scan_deg(const int* __restrict__ cnt, int* __restrict__ off) {
    __shared__ int psum[256];
    __shared__ int ex[256];
    int t = threadIdx.x;
    const int chunk = (NN + 255) / 256;
    int lo = t * chunk;
    int hi = lo + chunk; if (hi > NN) hi = NN; if (lo > NN) lo = NN;
    int s = 0;
    for (int i = lo; i < hi; ++i) s += cnt[i];
    psum[t] = s;
    __syncthreads();
    if (t == 0) {
        int run = 0;
        for (int i = 0; i < 256; ++i) { ex[i] = run; run += psum[i]; }
    }
    __syncthreads();
    int run = ex[t];
    for (int i = lo; i < hi; ++i) { off[i] = run; run += cnt[i]; }
    if (t == 0) off[NN] = NE;
}

// ---- CSR pass C: atomic-free, XCD-sliced scatter --------------------------
__global__ __launch_bounds__(256) void fill_sliced(const int* __restrict__ ei,
                                                   const int* __restrict__ off,
                                                   const int* __restrict__ pk,
                                                   int* __restrict__ ssrc) {
    int slice = blockIdx.x & 7;
    int chunk = blockIdx.x >> 3;                      // 0..127
    int lo = slice * NSLICE, hi = lo + NSLICE;
    int e0 = chunk * 5000, e1 = e0 + 5000;
    for (int e = e0 + threadIdx.x; e < e1; e += 256) {
        int p = pk[e];
        int dst = p & 32767, rank = p >> 15;
        if (dst >= lo && dst < hi)
            ssrc[off[dst] + rank] = ei[e];
    }
}

// ---- aggregate half (bf16, 64ch rows): out[n] = in[n] + sum in[src[e]] ----
// one wave/node: 8 edge-slots x 8 ch-groups (16B loads, 128B rows); unroll 4
__global__ __launch_bounds__(256) void agg_half(const u16* __restrict__ in, u16* __restrict__ out,
                                                const int* __restrict__ off, const int* __restrict__ ssrc) {
    int n = (blockIdx.x * 256 + threadIdx.x) >> 6;
    int lane = threadIdx.x & 63;
    int slot = lane >> 3, cg = lane & 7;
    int boff = cg * 8;
    float acc[8];
    if (slot == 0) {
        short8 v = *(const short8*)(in + (size_t)n * HC + boff);
        #pragma unroll
        for (int j = 0; j < 8; ++j) acc[j] = b2f((u16)v[j]);
    } else {
        #pragma unroll
        for (int j = 0; j < 8; ++j) acc[j] = 0.f;
    }
    int b = off[n], e = off[n + 1];
    int i = b + slot;
    for (; i + 24 < e; i += 32) {
        int s0 = ssrc[i], s1 = ssrc[i + 8], s2 = ssrc[i + 16], s3 = ssrc[i + 24];
        short8 v0 = *(const short8*)(in + (size_t)s0 * HC + boff);
        short8 v1 = *(const short8*)(in + (size_t)s1 * HC + boff);
        short8 v2 = *(const short8*)(in + (size_t)s2 * HC + boff);
        short8 v3 = *(const short8*)(in + (size_t)s3 * HC + boff);
        #pragma unroll
        for (int j = 0; j < 8; ++j)
            acc[j] += (b2f((u16)v0[j]) + b2f((u16)v1[j])) + (b2f((u16)v2[j]) + b2f((u16)v3[j]));
    }
    for (; i < e; i += 8) {
        int s0 = ssrc[i];
        short8 v0 = *(const short8*)(in + (size_t)s0 * HC + boff);
        #pragma unroll
        for (int j = 0; j < 8; ++j) acc[j] += b2f((u16)v0[j]);
    }
    #pragma unroll
    for (int j = 0; j < 8; ++j) {
        acc[j] += __shfl_xor(acc[j], 8);
        acc[j] += __shfl_xor(acc[j], 16);
        acc[j] += __shfl_xor(acc[j], 32);
    }
    if (slot == 0) {
        short8 o;
        #pragma unroll
        for (int j = 0; j < 8; ++j) o[j] = (short)f2b(acc[j]);
        *(short8*)(out + (size_t)n * HC + boff) = o;
    }
}

// ---- fused MLP: out = relu( relu(A@Wa+ba) @ Wb + bb ), split-layout A/out --
__global__ __launch_bounds__(256) void mlp_fused(const u16* __restrict__ A,
                                                 const u16* __restrict__ wtA, const u16* __restrict__ wtB,
                                                 const float* __restrict__ biasA, const float* __restrict__ biasB,
                                                 u16* __restrict__ out) {
    __shared__ u16 H[128 * 136];
    int t = threadIdx.x, wave = t >> 6, lane = t & 63;
    int quad = lane >> 4, l16 = lane & 15;
    int row0 = blockIdx.x * 128 + wave * 32;
    const u16* A0 = A;
    const u16* A1 = A + (size_t)NN * HC;
    u16* O0 = out;
    u16* O1 = out + (size_t)NN * HC;

    short8 af[2][4];                                   // A[m=l16][k=quad*8+j]
    #pragma unroll
    for (int rt = 0; rt < 2; ++rt) {
        int r = row0 + rt * 16 + l16; if (r >= NN) r = NN - 1;
        #pragma unroll
        for (int kc = 0; kc < 4; ++kc) {
            int k = kc * 32 + quad * 8;
            const u16* Ah = (k < HC) ? A0 : A1;
            af[rt][kc] = *(const short8*)(Ah + (size_t)r * HC + (k & 63));
        }
    }

    #pragma unroll
    for (int ct = 0; ct < 8; ++ct) {
        floatx4 a0 = (floatx4)(0.f), a1 = (floatx4)(0.f);
        #pragma unroll
        for (int kc = 0; kc < 4; ++kc) {
            short8 bf = *(const short8*)(wtA + (((ct * 4 + kc) * 4 + quad) * 16 + l16) * 8);
            a0 = __builtin_amdgcn_mfma_f32_16x16x32_bf16(af[0][kc], bf, a0, 0, 0, 0);
            a1 = __builtin_amdgcn_mfma_f32_16x16x32_bf16(af[1][kc], bf, a1, 0, 0, 0);
        }
        float bv = biasA[ct * 16 + l16];
        #pragma unroll
        for (int r = 0; r < 4; ++r) {
            int lr0 = wave * 32 + 0 * 16 + quad * 4 + r;   // C/D: row=quad*4+r, col=l16
            int lr1 = wave * 32 + 1 * 16 + quad * 4 + r;
            H[lr0 * 136 + ct * 16 + l16] = f2b(fmaxf(a0[r] + bv, 0.f));
            H[lr1 * 136 + ct * 16 + l16] = f2b(fmaxf(a1[r] + bv, 0.f));
        }
    }

    short8 af2[2][4];                                   // wave-private H rows
    #pragma unroll
    for (int rt = 0; rt < 2; ++rt)
        #pragma unroll
        for (int kc = 0; kc < 4; ++kc)
            af2[rt][kc] = *(const short8*)&H[(wave * 32 + rt * 16 + l16) * 136 + kc * 32 + quad * 8];

    #pragma unroll
    for (int ct = 0; ct < 8; ++ct) {
        floatx4 a0 = (floatx4)(0.f), a1 = (floatx4)(0.f);
        #pragma unroll
        for (int kc = 0; kc < 4; ++kc) {
            short8 bf = *(const short8*)(wtB + (((ct * 4 + kc) * 4 + quad) * 16 + l16) * 8);
            a0 = __builtin_amdgcn_mfma_f32_16x16x32_bf16(af2[0][kc], bf, a0, 0, 0, 0);
            a1 = __builtin_amdgcn_mfma_f32_16x16x32_bf16(af2[1][kc], bf, a1, 0, 0, 0);
        }
        int col = ct * 16 + l16;
        int half = col >> 6, c2 = col & 63;
        u16* Oh = half ? O1 : O0;
        float bv = biasB[col];
        #pragma unroll
        for (int rt = 0; rt < 2; ++rt) {
            floatx4 av = rt ? a1 : a0;
            #pragma unroll
            for (int r = 0; r < 4; ++r) {
                int row = row0 + rt * 16 + quad * 4 + r;
                if (row < NN)
                    Oh[(size_t)row * HC + c2] = f2b(fmaxf(av[r] + bv, 0.f));
            }
        }
    }
}

// ---- pool: run-length partial sums -> atomics, then per-graph fc ----------
__global__ __launch_bounds__(256) void pool_partial(const u16* __restrict__ h, const int* __restrict__ batch,
                                                    float* __restrict__ gsum) {
    int n0 = blockIdx.x * 40;
    int n1 = n0 + 40; if (n1 > NN) n1 = NN;
    int half2 = threadIdx.x >> 7, c = threadIdx.x & 127;
    int hsel = c >> 6, c2 = c & 63;
    const u16* hh = h + (size_t)hsel * NN * HC;
    float run = 0.f; int curg = -1;
    for (int n = n0 + half2; n < n1; n += 2) {
        int g = batch[n];
        if (g != curg) {
            if (curg >= 0) atomicAdd(&gsum[curg * CH + c], run);
            run = 0.f; curg = g;
        }
        run += b2f(hh[(size_t)n * HC + c2]);
    }
    if (curg >= 0) atomicAdd(&gsum[curg * CH + c], run);
}

__global__ __launch_bounds__(128) void pool_final(const float* __restrict__ gsum, const int* __restrict__ batch,
                                                  const float* __restrict__ fcw, const float* __restrict__ fcb,
                                                  float* __restrict__ outp) {
    int g = blockIdx.x, t = threadIdx.x;
    __shared__ int se[2];
    if (t < 2) {
        int target = g + t, lo = 0, hi = NN;
        while (lo < hi) { int mid = (lo + hi) >> 1; if (batch[mid] < target) lo = mid + 1; else hi = mid; }
        se[t] = lo;
    }
    __syncthreads();
    int cnt = se[1] - se[0]; if (cnt < 1) cnt = 1;
    float v = gsum[g * CH + t] * fcw[t] / (float)cnt;
    __shared__ float red[128];
    red[t] = v; __syncthreads();
    for (int s = 64; s > 0; s >>= 1) { if (t < s) red[t] += red[t + s]; __syncthreads(); }
    if (t == 0) outp[g] = red[0] + fcb[0];
}

extern "C" void kernel_launch(void* const* d_in, const int* in_sizes, int n_in,
                              void* d_out, int out_size, void* d_ws, size_t ws_size,
                              hipStream_t stream) {
    const float* x   = (const float*)d_in[0];
    const int*   ei  = (const int*)d_in[1];
    const int* batch = (const int*)d_in[2];
    const float* W1a = (const float*)d_in[3];
    const float* b1a = (const float*)d_in[4];
    const float* W1b = (const float*)d_in[5];
    const float* b1b = (const float*)d_in[6];
    const float* W2a = (const float*)d_in[7];
    const float* b2a = (const float*)d_in[8];
    const float* W2b = (const float*)d_in[9];
    const float* b2b = (const float*)d_in[10];
    const float* fcw = (const float*)d_in[11];
    const float* fcb = (const float*)d_in[12];
    float* out = (float*)d_out;

    char* w = (char*)d_ws;
    u16* xb   = (u16*)w; w += (size_t)NN * CH * 2;   // split: [2][NN][64]
    u16* bufA = (u16*)w; w += (size_t)NN * CH * 2;   // split
    u16* bufB = (u16*)w; w += (size_t)NN * CH * 2;   // split
    u16* wt   = (u16*)w; w += (size_t)4 * 16384 * 2;
    int* cnt  = (int*)w; w += (size_t)NN * 4;
    float* gsum = (float*)w; w += (size_t)NG * CH * 4;
    int* off  = (int*)w; w += (size_t)(NN + 1) * 4;
    int* pk   = (int*)w; w += (size_t)NE * 4;
    int* ssrc = (int*)w; w += (size_t)NE * 4;

    hipMemsetAsync(cnt, 0, (size_t)(NN + NG * CH) * 4, stream);

    cvt_all<<<2756, 256, 0, stream>>>(x, xb, W1a, W1b, W2a, W2b, wt);
    pass_rank<<<(NE + 255) / 256, 256, 0, stream>>>(ei, cnt, pk);
    scan_deg<<<1, 256, 0, stream>>>(cnt, off);
    fill_sliced<<<1024, 256, 0, stream>>>(ei, off, pk, ssrc);

    const size_t HS = (size_t)NN * HC;
    // layer 1
    agg_half<<<5000, 256, 0, stream>>>(xb,      bufA,      off, ssrc);
    agg_half<<<5000, 256, 0, stream>>>(xb + HS, bufA + HS, off, ssrc);
    mlp_fused<<<157, 256, 0, stream>>>(bufA, wt + 0 * 16384, wt + 1 * 16384, b1a, b1b, bufB);
    // layer 2
    agg_half<<<5000, 256, 0, stream>>>(bufB,      bufA,      off, ssrc);
    agg_half<<<5000, 256, 0, stream>>>(bufB + HS, bufA + HS, off, ssrc);
    mlp_fused<<<157, 256, 0, stream>>>(bufA, wt + 2 * 16384, wt + 3 * 16384, b2a, b2b, bufB);
    // pool + fc
    pool_partial<<<500, 256, 0, stream>>>(bufB, batch, gsum);
    pool_final<<<NG, 128, 0, stream>>>(gsum, batch, fcw, fcb, out);
}